// Round 13
// baseline (394.443 us; speedup 1.0000x reference)
//
#include <hip/hip_runtime.h>
#include <cstdint>
#include <cstddef>

#define T_TOKENS 8192
#define K_DIM 4096
#define N_DIM 4096
#define K_TILES 32  // K_DIM / 128

#define PACK_BLOCKS (N_DIM * K_DIM / 4 / 256)  // 16384 blocks of 256 threads
#define QUANT_BLOCKS T_TOKENS                  // 8192 blocks

using i32x4 = __attribute__((ext_vector_type(4))) int;

// ---------------------------------------------------------------------------
// Kernel 0: fused prep (verified; ~memory floor).
// ---------------------------------------------------------------------------
__global__ __launch_bounds__(256) void prep(const int* __restrict__ win,
                                            int8_t* __restrict__ wout,
                                            const float* __restrict__ x,
                                            int8_t* __restrict__ qx,
                                            float* __restrict__ xscale) {
    const int bid = blockIdx.x;
    const int tid = threadIdx.x;

    if (bid < PACK_BLOCKS) {
        const int idx = bid * 256 + tid;  // one dword (4 int8) out
        const i32x4 v = reinterpret_cast<const i32x4*>(win)[idx];
        uint32_t pk = (uint32_t)(v.x & 255) | ((uint32_t)(v.y & 255) << 8) |
                      ((uint32_t)(v.z & 255) << 16) | ((uint32_t)(v.w & 255) << 24);
        reinterpret_cast<int*>(wout)[idx] = (int)pk;
        return;
    }

    const int t = bid - PACK_BLOCKS;
    const float4* row = reinterpret_cast<const float4*>(x + (size_t)t * K_DIM);

    float4 v[4];
    float amax = 0.0f;
#pragma unroll
    for (int i = 0; i < 4; ++i) {
        v[i] = row[i * 256 + tid];
        amax = fmaxf(amax, fabsf(v[i].x));
        amax = fmaxf(amax, fabsf(v[i].y));
        amax = fmaxf(amax, fabsf(v[i].z));
        amax = fmaxf(amax, fabsf(v[i].w));
    }
#pragma unroll
    for (int off = 32; off > 0; off >>= 1)
        amax = fmaxf(amax, __shfl_xor(amax, off));

    __shared__ float red[4];
    if ((tid & 63) == 0) red[tid >> 6] = amax;
    __syncthreads();
    amax = fmaxf(fmaxf(red[0], red[1]), fmaxf(red[2], red[3]));

    const float scale = fmaxf(amax, 1e-30f) * (1.0f / 127.0f);
    if (tid == 0) xscale[t] = scale;

    const float inv = 1.0f / scale;
    int* qrow = reinterpret_cast<int*>(qx + (size_t)t * K_DIM);
#pragma unroll
    for (int i = 0; i < 4; ++i) {
        int q0 = (int)fminf(fmaxf(rintf(v[i].x * inv), -127.0f), 127.0f);
        int q1 = (int)fminf(fmaxf(rintf(v[i].y * inv), -127.0f), 127.0f);
        int q2 = (int)fminf(fmaxf(rintf(v[i].z * inv), -127.0f), 127.0f);
        int q3 = (int)fminf(fmaxf(rintf(v[i].w * inv), -127.0f), 127.0f);
        uint32_t pk = (uint32_t)(q0 & 255) | ((uint32_t)(q1 & 255) << 8) |
                      ((uint32_t)(q2 & 255) << 16) | ((uint32_t)(q3 & 255) << 24);
        qrow[i * 256 + tid] = (int)pk;
    }
}

// ---------------------------------------------------------------------------
// Kernel 1: int8 GEMM — 256x256/BK=128 tile (FETCH-optimal, r2-verified)
// with SIXTEEN waves per block (1024 threads, 4M x 4N, 64x64 per wave).
// acc = 64 regs/wave -> total live ~110 <= 128 -> 4 waves/SIMD resident in
// the single 128-KiB-LDS block (r6 spilled because it kept acc=128; this
// keeps the full tile AND halves the accumulator).  Doubles the wave pool
// available to the CU scheduler during vmcnt/barrier drains (m114 overlap)
// without touching arithmetic intensity.
//
// LDS layout, XOR swizzle (16-row x 4-chunk fragment geometry, verified
// 0-conflict), global_load_lds width-16 staging, XCD block swizzle: all
// byte-identical to r10/r12.
//
// Schedule: 2 publishes/tile.  Slabs per tile: A0 B0 A1 B1, ONE gload per
// thread per slab (1024 threads x 16 B = 16 KB slab).  Ledger: prologue 4
// outstanding; ph0 issues A0',B0' -> 6, vmcnt(4) drains A0,B0; ph1 issues
// A1',B1' -> 6, vmcnt(4) drains A1,B1.  Tail: vmcnt(2) then vmcnt(0).
//
// Closed doors (measured): tile shrink (r2), 32x32 MFMA (r4), fewer
// barriers at 8 waves (r5), BK=64 @(512,4) acc spill (r6), batched publish
// (r8), B-from-global (r9), pre-MFMA barrier (r11).
// Revert signal this round: WRITE_SIZE >> 131 MB (spill) or GEMM >= 134us.
// ---------------------------------------------------------------------------
__global__ __launch_bounds__(1024, 4) void int8_gemm(const int8_t* __restrict__ qx,
                                                     const int8_t* __restrict__ w,
                                                     const float* __restrict__ xscale,
                                                     const float* __restrict__ wscale,
                                                     const float* __restrict__ bias,
                                                     float* __restrict__ out) {
    extern __shared__ int8_t lds[];  // 131072 bytes: [buf:2][op:2][ksl:2][256][64]

    const int tid = threadIdx.x;
    const int lane = tid & 63;
    const int wave = tid >> 6;     // 0..15
    const int wr = wave >> 2;      // 0..3 : 64 token rows each
    const int wn = wave & 3;       // 0..3 : 64 feature cols each
    const int l16 = lane & 15;
    const int quad = lane >> 4;

    // XCD-aware swizzle: 512 blocks, 64 contiguous per XCD, M-major chunks.
    const int wg = ((blockIdx.x & 7) << 6) | ((int)blockIdx.x >> 3);
    const int tm = wg >> 4;  // 0..31
    const int tn = wg & 15;  // 0..15

    const int8_t* gA = qx + (size_t)tm * 256 * K_DIM;
    const int8_t* gB = w + (size_t)tn * 256 * K_DIM;

    // staging: 1024 threads cover one 16-KB slab (256 rows x 64 B) per gload:
    // row = tid>>2, 16-B chunk = tid&3, source col pre-swizzled (linear LDS
    // dest; both-sides involution).
    const int s_row = tid >> 2;
    const int scol = (((tid & 3) ^ ((s_row >> 1) & 3)) << 4);
    // fragment read col: chunk quad of row base+l16 (verified 0-conflict)
    const int fcol = ((quad ^ ((l16 >> 1) & 3)) << 4);

    const int ldsA_rd = (wr * 64 + l16) * 64 + fcol;            // + mi*1024
    const int ldsB_rd = 32768 + (wn * 64 + l16) * 64 + fcol;    // + nj*1024

#define STAGE1(buf, op, ksl, k0)                                                        \
    {                                                                                   \
        const int8_t* g_ = ((op) ? gB : gA) +                                           \
                           ((size_t)s_row * K_DIM + (size_t)((k0) + (ksl) * 64 + scol));\
        int8_t* l_ = lds + (buf) * 65536 + (op) * 32768 + (ksl) * 16384 + tid * 16;     \
        __builtin_amdgcn_global_load_lds(                                               \
            (const __attribute__((address_space(1))) void*)g_,                          \
            (__attribute__((address_space(3))) void*)l_, 16, 0, 0);                     \
    }

    i32x4 acc[4][4] = {};   // 64 regs: [mi][nj] 16x16 tiles
    i32x4 af[4], bf[4];

#define READ_AB(buf, ksl)                                                    \
    {                                                                        \
        const int8_t* sA_ = lds + (buf) * 65536 + (ksl) * 16384 + ldsA_rd;   \
        const int8_t* sB_ = lds + (buf) * 65536 + (ksl) * 16384 + ldsB_rd;   \
        _Pragma("unroll") for (int mi = 0; mi < 4; ++mi)                     \
            af[mi] = *(const i32x4*)(sA_ + mi * 1024);                       \
        _Pragma("unroll") for (int nj = 0; nj < 4; ++nj)                     \
            bf[nj] = *(const i32x4*)(sB_ + nj * 1024);                       \
    }
#define MFMA16()                                                             \
    __builtin_amdgcn_s_setprio(1);                                           \
    _Pragma("unroll") for (int mi = 0; mi < 4; ++mi) {                       \
        _Pragma("unroll") for (int nj = 0; nj < 4; ++nj)                     \
            acc[mi][nj] = __builtin_amdgcn_mfma_i32_16x16x64_i8(             \
                af[mi], bf[nj], acc[mi][nj], 0, 0, 0);                       \
    }                                                                        \
    __builtin_amdgcn_s_setprio(0);

    // prologue: stage tile 0 into buf 0, order A0 B0 A1 B1 (oldest first)
    STAGE1(0, 0, 0, 0)
    STAGE1(0, 1, 0, 0)
    STAGE1(0, 0, 1, 0)
    STAGE1(0, 1, 1, 0)

    for (int t = 0; t < K_TILES - 1; ++t) {
        const int cur = t & 1;
        const int nxt = cur ^ 1;
        const int k1 = (t + 1) << 7;

        // phase 0 (ksl0): prefetch A0',B0' ; publish A0,B0 ; 16 MFMA
        STAGE1(nxt, 0, 0, k1)
        STAGE1(nxt, 1, 0, k1)
        asm volatile("s_waitcnt vmcnt(4)" ::: "memory");
        __builtin_amdgcn_s_barrier();
        READ_AB(cur, 0)
        MFMA16()
        __builtin_amdgcn_s_barrier();

        // phase 1 (ksl1): prefetch A1',B1' ; publish A1,B1 ; 16 MFMA
        STAGE1(nxt, 0, 1, k1)
        STAGE1(nxt, 1, 1, k1)
        asm volatile("s_waitcnt vmcnt(4)" ::: "memory");
        __builtin_amdgcn_s_barrier();
        READ_AB(cur, 1)
        MFMA16()
        __builtin_amdgcn_s_barrier();  // buf[cur] reads done before t+1 stages it
    }

    // tail tile (t = K_TILES-1, buf = 1): no prefetch; drain 2 -> 0
    {
        asm volatile("s_waitcnt vmcnt(2)" ::: "memory");
        __builtin_amdgcn_s_barrier();
        READ_AB(1, 0)
        MFMA16()
        __builtin_amdgcn_s_barrier();
        asm volatile("s_waitcnt vmcnt(0)" ::: "memory");
        __builtin_amdgcn_s_barrier();
        READ_AB(1, 1)
        MFMA16()
    }

    // epilogue: dequant + bias.  C/D: col = l16, row = quad*4 + reg.
    const int row_base = tm * 256 + wr * 64 + quad * 4;
    const int col_base = tn * 256 + wn * 64 + l16;
    float wsv[4], bsv[4];
#pragma unroll
    for (int nj = 0; nj < 4; ++nj) {
        wsv[nj] = wscale[col_base + nj * 16];
        bsv[nj] = bias[col_base + nj * 16];
    }
#pragma unroll
    for (int mi = 0; mi < 4; ++mi) {
#pragma unroll
        for (int r = 0; r < 4; ++r) {
            const int trow = row_base + mi * 16 + r;
            const float xs = xscale[trow];
            float* orow = out + (size_t)trow * N_DIM + col_base;
#pragma unroll
            for (int nj = 0; nj < 4; ++nj)
                orow[nj * 16] = (float)acc[mi][nj][r] * (wsv[nj] * xs) + bsv[nj];
        }
    }
#undef STAGE1
#undef READ_AB
#undef MFMA16
}

extern "C" void kernel_launch(void* const* d_in, const int* in_sizes, int n_in,
                              void* d_out, int out_size, void* d_ws, size_t ws_size,
                              hipStream_t stream) {
    const float* x = (const float*)d_in[0];
    const int* w_i32 = (const int*)d_in[1];  // harness delivers int8 ref input as int32
    const float* wscale = (const float*)d_in[2];
    const float* bias = (const float*)d_in[3];
    float* out = (float*)d_out;

    // workspace: qx (32 MB) | xscale (32 KB pad to 64 KB) | packed weight (16 MB)
    int8_t* qx = (int8_t*)d_ws;
    float* xscale = (float*)((char*)d_ws + (size_t)T_TOKENS * K_DIM);
    int8_t* wpk = (int8_t*)((char*)d_ws + (size_t)T_TOKENS * K_DIM + 65536);

    static bool attr_set = false;
    if (!attr_set) {
        (void)hipFuncSetAttribute(reinterpret_cast<const void*>(&int8_gemm),
                                  hipFuncAttributeMaxDynamicSharedMemorySize, 131072);
        attr_set = true;
    }

    prep<<<PACK_BLOCKS + QUANT_BLOCKS, 256, 0, stream>>>(w_i32, wpk, x, qx, xscale);

    int8_gemm<<<dim3(512), dim3(1024), 131072, stream>>>(qx, wpk, xscale, wscale, bias, out);
}

// Round 14
// 382.968 us; speedup vs baseline: 1.0300x; 1.0300x over previous
//
#include <hip/hip_runtime.h>
#include <cstdint>
#include <cstddef>

#define T_TOKENS 8192
#define K_DIM 4096
#define N_DIM 4096
#define K_TILES 32  // K_DIM / 128

#define PACK_BLOCKS (N_DIM * K_DIM / 4 / 256)  // 16384 blocks of 256 threads
#define QUANT_BLOCKS T_TOKENS                  // 8192 blocks

using i32x4 = __attribute__((ext_vector_type(4))) int;

// ---------------------------------------------------------------------------
// Kernel 0: fused prep (verified; ~memory floor).
// ---------------------------------------------------------------------------
__global__ __launch_bounds__(256) void prep(const int* __restrict__ win,
                                            int8_t* __restrict__ wout,
                                            const float* __restrict__ x,
                                            int8_t* __restrict__ qx,
                                            float* __restrict__ xscale) {
    const int bid = blockIdx.x;
    const int tid = threadIdx.x;

    if (bid < PACK_BLOCKS) {
        const int idx = bid * 256 + tid;  // one dword (4 int8) out
        const i32x4 v = reinterpret_cast<const i32x4*>(win)[idx];
        uint32_t pk = (uint32_t)(v.x & 255) | ((uint32_t)(v.y & 255) << 8) |
                      ((uint32_t)(v.z & 255) << 16) | ((uint32_t)(v.w & 255) << 24);
        reinterpret_cast<int*>(wout)[idx] = (int)pk;
        return;
    }

    const int t = bid - PACK_BLOCKS;
    const float4* row = reinterpret_cast<const float4*>(x + (size_t)t * K_DIM);

    float4 v[4];
    float amax = 0.0f;
#pragma unroll
    for (int i = 0; i < 4; ++i) {
        v[i] = row[i * 256 + tid];
        amax = fmaxf(amax, fabsf(v[i].x));
        amax = fmaxf(amax, fabsf(v[i].y));
        amax = fmaxf(amax, fabsf(v[i].z));
        amax = fmaxf(amax, fabsf(v[i].w));
    }
#pragma unroll
    for (int off = 32; off > 0; off >>= 1)
        amax = fmaxf(amax, __shfl_xor(amax, off));

    __shared__ float red[4];
    if ((tid & 63) == 0) red[tid >> 6] = amax;
    __syncthreads();
    amax = fmaxf(fmaxf(red[0], red[1]), fmaxf(red[2], red[3]));

    const float scale = fmaxf(amax, 1e-30f) * (1.0f / 127.0f);
    if (tid == 0) xscale[t] = scale;

    const float inv = 1.0f / scale;
    int* qrow = reinterpret_cast<int*>(qx + (size_t)t * K_DIM);
#pragma unroll
    for (int i = 0; i < 4; ++i) {
        int q0 = (int)fminf(fmaxf(rintf(v[i].x * inv), -127.0f), 127.0f);
        int q1 = (int)fminf(fmaxf(rintf(v[i].y * inv), -127.0f), 127.0f);
        int q2 = (int)fminf(fmaxf(rintf(v[i].z * inv), -127.0f), 127.0f);
        int q3 = (int)fminf(fmaxf(rintf(v[i].w * inv), -127.0f), 127.0f);
        uint32_t pk = (uint32_t)(q0 & 255) | ((uint32_t)(q1 & 255) << 8) |
                      ((uint32_t)(q2 & 255) << 16) | ((uint32_t)(q3 & 255) << 24);
        qrow[i * 256 + tid] = (int)pk;
    }
}

// ---------------------------------------------------------------------------
// Kernel 1: int8 GEMM — r10 VERIFIED BEST (133.4 us GEMM, 384.4 us total;
// MfmaUtil 45-47%, 0 bank conflicts, no spill).  256x256/BK=128, 8 waves
// 2Mx4N, mfma_i32_16x16x64_i8, 6-barrier lockstep rhythm, vmcnt(6)
// twice/tile, global_load_lds width-16 staging, both-sides XOR swizzle,
// XCD-aware block swizzle, mh1 A-fragment reads co-located with the mh0
// MFMA cluster (afB — the one schedule refinement that measured positive).
//
// Local-optimum evidence (all single-variable, all regress):
//   r2  tile 256x128                  -> FETCH x1.8, 151 us
//   r4  32x32x32 MFMA                 -> inherent 4-way LDS conflict, 153 us
//   r5  remove lockstep barriers      -> 140 us
//   r6  BK=64 @ (512,4)               -> acc spill, WRITE 2.9 GB, 892 us
//   r8  batched publish+hoisted reads -> 158 us
//   r9  B direct-from-global          -> 16-segment gathers, 236 us
//   r11 pre-MFMA barrier (m201 style) -> 139 us
//   r13 16 waves/block (4/SIMD, occ 40%) -> 144 us (barrier spread + LDS
//       read amplification beat the occupancy gain; m114 overlap needs
//       INDEPENDENT blocks, which the 128-reg accumulator forbids)
// GEMM = 2.06 POPS = 52% of the i8 MFMA ubench ceiling, sync-bound; the
// residual is the lockstep-template penalty whose component grafts are
// null/negative (r8, r11, r13).  Non-GEMM ~250 us = prep memory floor
// (~40 us) + fixed harness overhead, invariant under prep restructuring.
// ---------------------------------------------------------------------------
__global__ __launch_bounds__(512, 2) void int8_gemm(const int8_t* __restrict__ qx,
                                                    const int8_t* __restrict__ w,
                                                    const float* __restrict__ xscale,
                                                    const float* __restrict__ wscale,
                                                    const float* __restrict__ bias,
                                                    float* __restrict__ out) {
    extern __shared__ int8_t lds[];  // 131072 bytes

    const int tid = threadIdx.x;
    const int lane = tid & 63;
    const int wave = tid >> 6;
    const int wr = wave >> 2;  // 0..1 : 128 token rows
    const int wn = wave & 3;   // 0..3 : 64 feature cols
    const int l16 = lane & 15;
    const int quad = lane >> 4;

    // XCD-aware swizzle: 512 blocks, 64 contiguous per XCD, M-major chunks.
    const int wg = ((blockIdx.x & 7) << 6) | ((int)blockIdx.x >> 3);
    const int tm = wg >> 4;  // 0..31
    const int tn = wg & 15;  // 0..15

    const int8_t* gA = qx + (size_t)tm * 256 * K_DIM;
    const int8_t* gB = w + (size_t)tn * 256 * K_DIM;

    // staging: thread covers rows (tid>>2), (tid>>2)+128; 16B chunk (tid&3),
    // source col pre-swizzled (linear LDS dest; both-sides involution).
    const int s_row = tid >> 2;
    const int scol = (((tid & 3) ^ ((s_row >> 1) & 3)) << 4);
    // fragment read col: chunk quad of row base+l16 (verified 0-conflict)
    const int fcol = ((quad ^ ((l16 >> 1) & 3)) << 4);

    const int ldsA_rd = (wr * 128 + l16) * 64 + fcol;           // + mh*4096 + q*1024
    const int ldsB_rd = 32768 + (wn * 64 + l16) * 64 + fcol;    // + nj*1024

#define STAGE2(buf, op, ksl, k0)                                                        \
    {                                                                                   \
        const int8_t* g_ = ((op) ? gB : gA) +                                           \
                           ((size_t)s_row * K_DIM + (size_t)((k0) + (ksl) * 64 + scol));\
        int8_t* l_ = lds + (buf) * 65536 + (op) * 32768 + (ksl) * 16384 + tid * 16;     \
        __builtin_amdgcn_global_load_lds(                                               \
            (const __attribute__((address_space(1))) void*)g_,                          \
            (__attribute__((address_space(3))) void*)l_, 16, 0, 0);                     \
        __builtin_amdgcn_global_load_lds(                                               \
            (const __attribute__((address_space(1))) void*)(g_ + (size_t)128 * K_DIM),  \
            (__attribute__((address_space(3))) void*)(l_ + 8192), 16, 0, 0);            \
    }

    i32x4 acc[8][4] = {};
    i32x4 afA[4], afB[4], bf[4];  // afB: mh1 frags, read one region early

#define READ_B(buf, ksl)                                                     \
    {                                                                        \
        const int8_t* sB_ = lds + (buf) * 65536 + (ksl) * 16384 + ldsB_rd;   \
        _Pragma("unroll") for (int nj = 0; nj < 4; ++nj)                     \
            bf[nj] = *(const i32x4*)(sB_ + nj * 1024);                       \
    }
#define READ_A(DST, buf, ksl, mh)                                            \
    {                                                                        \
        const int8_t* sA_ =                                                  \
            lds + (buf) * 65536 + (ksl) * 16384 + (mh) * 4096 + ldsA_rd;     \
        _Pragma("unroll") for (int q = 0; q < 4; ++q)                        \
            DST[q] = *(const i32x4*)(sA_ + q * 1024);                        \
    }
#define MFMA16(mh, SET)                                                      \
    __builtin_amdgcn_s_setprio(1);                                           \
    _Pragma("unroll") for (int q = 0; q < 4; ++q) {                          \
        _Pragma("unroll") for (int nj = 0; nj < 4; ++nj)                     \
            acc[(mh) * 4 + q][nj] = __builtin_amdgcn_mfma_i32_16x16x64_i8(   \
                SET[q], bf[nj], acc[(mh) * 4 + q][nj], 0, 0, 0);             \
    }                                                                        \
    __builtin_amdgcn_s_setprio(0);

    // prologue: stage tile 0 into buf 0, order A0 B0 A1 B1 (oldest first)
    STAGE2(0, 0, 0, 0)
    STAGE2(0, 1, 0, 0)
    STAGE2(0, 0, 1, 0)
    STAGE2(0, 1, 1, 0)

    // Steady-state vmcnt ledger (each STAGE2 = 2 gloads):
    //  ph0: issue A0(t+1) -> 10 outstanding; vmcnt(6) drains A0(t),B0(t)
    //  ph2: issue A1(t+1) -> 10 outstanding; vmcnt(6) drains A1(t),B1(t)
    for (int t = 0; t < K_TILES - 1; ++t) {
        const int cur = t & 1;
        const int nxt = cur ^ 1;
        const int k1 = (t + 1) << 7;

        // phase 0: (ksl0, mh0) ; prefetch A-slab0(t+1); mh1 reads co-located
        STAGE2(nxt, 0, 0, k1)
        asm volatile("s_waitcnt vmcnt(6)" ::: "memory");
        __builtin_amdgcn_s_barrier();
        READ_B(cur, 0)
        READ_A(afA, cur, 0, 0)
        READ_A(afB, cur, 0, 1)   // mh1 frags: latency hides under MFMA16(0)
        MFMA16(0, afA)
        __builtin_amdgcn_s_barrier();

        // phase 1: (ksl0, mh1) ; prefetch B-slab0(t+1)
        STAGE2(nxt, 1, 0, k1)
        MFMA16(1, afB)
        __builtin_amdgcn_s_barrier();

        // phase 2: (ksl1, mh0) ; prefetch A-slab1(t+1); mh1 reads co-located
        STAGE2(nxt, 0, 1, k1)
        asm volatile("s_waitcnt vmcnt(6)" ::: "memory");
        __builtin_amdgcn_s_barrier();
        READ_B(cur, 1)
        READ_A(afA, cur, 1, 0)
        READ_A(afB, cur, 1, 1)
        MFMA16(0, afA)
        __builtin_amdgcn_s_barrier();

        // phase 3: (ksl1, mh1) ; prefetch B-slab1(t+1)
        STAGE2(nxt, 1, 1, k1)
        MFMA16(1, afB)
        __builtin_amdgcn_s_barrier();
    }

    // tail tile (t = K_TILES-1, buf = 1): no prefetch; drain counted 4 -> 0
    {
        asm volatile("s_waitcnt vmcnt(4)" ::: "memory");
        __builtin_amdgcn_s_barrier();
        READ_B(1, 0)
        READ_A(afA, 1, 0, 0)
        READ_A(afB, 1, 0, 1)
        MFMA16(0, afA)
        __builtin_amdgcn_s_barrier();
        MFMA16(1, afB)
        __builtin_amdgcn_s_barrier();
        asm volatile("s_waitcnt vmcnt(0)" ::: "memory");
        __builtin_amdgcn_s_barrier();
        READ_B(1, 1)
        READ_A(afA, 1, 1, 0)
        READ_A(afB, 1, 1, 1)
        MFMA16(0, afA)
        __builtin_amdgcn_s_barrier();
        MFMA16(1, afB)
    }

    // epilogue: dequant + bias.  C/D: col = l16, row = quad*4 + reg.
    const int row_base = tm * 256 + wr * 128 + quad * 4;
    const int col_base = tn * 256 + wn * 64 + l16;
    float wsv[4], bsv[4];
#pragma unroll
    for (int nj = 0; nj < 4; ++nj) {
        wsv[nj] = wscale[col_base + nj * 16];
        bsv[nj] = bias[col_base + nj * 16];
    }
#pragma unroll
    for (int mi = 0; mi < 8; ++mi) {
#pragma unroll
        for (int r = 0; r < 4; ++r) {
            const int trow = row_base + mi * 16 + r;
            const float xs = xscale[trow];
            float* orow = out + (size_t)trow * N_DIM + col_base;
#pragma unroll
            for (int nj = 0; nj < 4; ++nj)
                orow[nj * 16] = (float)acc[mi][nj][r] * (wsv[nj] * xs) + bsv[nj];
        }
    }
#undef STAGE2
#undef READ_B
#undef READ_A
#undef MFMA16
}

extern "C" void kernel_launch(void* const* d_in, const int* in_sizes, int n_in,
                              void* d_out, int out_size, void* d_ws, size_t ws_size,
                              hipStream_t stream) {
    const float* x = (const float*)d_in[0];
    const int* w_i32 = (const int*)d_in[1];  // harness delivers int8 ref input as int32
    const float* wscale = (const float*)d_in[2];
    const float* bias = (const float*)d_in[3];
    float* out = (float*)d_out;

    // workspace: qx (32 MB) | xscale (32 KB pad to 64 KB) | packed weight (16 MB)
    int8_t* qx = (int8_t*)d_ws;
    float* xscale = (float*)((char*)d_ws + (size_t)T_TOKENS * K_DIM);
    int8_t* wpk = (int8_t*)((char*)d_ws + (size_t)T_TOKENS * K_DIM + 65536);

    static bool attr_set = false;
    if (!attr_set) {
        (void)hipFuncSetAttribute(reinterpret_cast<const void*>(&int8_gemm),
                                  hipFuncAttributeMaxDynamicSharedMemorySize, 131072);
        attr_set = true;
    }

    prep<<<PACK_BLOCKS + QUANT_BLOCKS, 256, 0, stream>>>(w_i32, wpk, x, qx, xscale);

    int8_gemm<<<dim3(512), dim3(512), 131072, stream>>>(qx, wpk, xscale, wscale, bias, out);
}